// Round 5
// baseline (212.437 us; speedup 1.0000x reference)
//
#include <hip/hip_runtime.h>
#include <cstdint>

#pragma clang fp contract(off)

#define NB      32
#define NC      18
#define NA      8400
#define NCH     (4 + NC)
#define TOPK    300
#define TARGET  316        // TOPK + margin: absorbs sigmoid-tie rank ambiguity
#define NBINS   4096
#define CAP     1024
#define CONF    0.25f
#define IOU_T   0.45f
#define NT      512
#define NW      (NT / 64)
// Prefilter: N(0,1) logits, top-316 cutoff ~1.75 +- 0.1; count(x>1.4) in [553,803] (5-sigma).
// Fast path requires TARGET <= s_cnt <= CAP, else exact fallback (R4 algorithm).
#define PREF_X  1.4f
// sigmoid(x) > 0.25  <=>  x > -ln(3). Outside [XLO,XHI] analytic compare is exact.
#define XHI     (-1.0984f)
#define XLO     (-1.0988f)

typedef unsigned long long ull;

__device__ __forceinline__ float sigmoidf(float x) {
    return 1.0f / (1.0f + expf(-x));
}
__device__ __forceinline__ unsigned int mono_key(unsigned int bits) {
    return (bits & 0x80000000u) ? ~bits : (bits | 0x80000000u);
}
__device__ __forceinline__ unsigned int mono_inv(unsigned int key) {
    return (key & 0x80000000u) ? (key ^ 0x80000000u) : ~key;
}
__device__ __forceinline__ bool conf_pass(float x) {
    if (x >= XHI) return true;
    if (x <= XLO) return false;
    return sigmoidf(x) > CONF;   // rare exact band (~1 element per task)
}
__device__ __forceinline__ unsigned int make_key(float x) {
    return conf_pass(x) ? mono_key(__float_as_uint(x)) : 0u;
}

// Suffix-find over hist: T1 s.t. count(bins > T1) < target <= count(bins >= T1).
// Requires *s_T1 == -1 on entry. Contains barriers (call from block-uniform flow).
__device__ __forceinline__ void suffix_find(unsigned int* hist, unsigned int* wtot,
                                            int target, int tid, int* s_T1) {
    const int base = tid * (NBINS / NT);   // 8 bins per thread
    unsigned int v = 0;
#pragma unroll
    for (int k = 0; k < NBINS / NT; ++k) v += hist[base + k];
    const int lane = tid & 63;
    unsigned int s = v;   // inclusive suffix sum within wave
#pragma unroll
    for (int d = 1; d < 64; d <<= 1) {
        unsigned int o = __shfl_down(s, d, 64);
        if (lane + d < 64) s += o;
    }
    if (lane == 0) wtot[tid >> 6] = s;
    __syncthreads();
    unsigned int above_waves = 0;
    for (int wv = (tid >> 6) + 1; wv < NW; ++wv) above_waves += wtot[wv];
    unsigned int acc = (s - v) + above_waves;  // strictly after this thread's chunk
    for (int bin = base + (NBINS / NT) - 1; bin >= base; --bin) {
        unsigned int cnt = hist[bin];
        if (acc < (unsigned int)target && acc + cnt >= (unsigned int)target) *s_T1 = bin;
        acc += cnt;
    }
    __syncthreads();
}

// LDS pool layout (manual phase aliasing):
//  A [0..16384):    hist (P2/fallback-hist) | cand2 @0 (8192 B) + skey @8192 (2400 B)
//  B [16384..24576): cand (ull[CAP])
//  C [24576..44976): box4 @24576 (4800) | bvv @29376 (1200) | supmask @30576 (300*48)
#define POOL_BYTES 44976
#define OFF_SKEY   8192
#define OFF_CAND   16384
#define OFF_BOX4   24576
#define OFF_BVV    29376
#define OFF_SUP    30576

__global__ __launch_bounds__(NT) void yolo_post(const float* __restrict__ in,
                                                float* __restrict__ out) {
    __shared__ __align__(16) unsigned char pool[POOL_BYTES];
    __shared__ unsigned int wtot[NW];
    __shared__ ull keepw[5];
    __shared__ unsigned int s_cnt, s_cnt2;
    __shared__ int s_T1;

    unsigned int* hist  = (unsigned int*)pool;
    ull*  cand2 = (ull*)pool;
    ull*  skey  = (ull*)(pool + OFF_SKEY);
    ull*  cand  = (ull*)(pool + OFF_CAND);
    float4* box4 = (float4*)(pool + OFF_BOX4);
    float*  bvv  = (float*)(pool + OFF_BVV);
    ull*  sup   = (ull*)(pool + OFF_SUP);   // [300][6], word 5 = pad

    const int tid = threadIdx.x;
    // XCD swizzle: image b -> XCD b%8 (blocks dispatched round-robin over 8 XCDs)
    const int x = blockIdx.x;
    const int b = (x & 7) + 8 * ((x >> 3) & 3);
    const int c = x >> 5;
    const float* cls = in + (size_t)b * NCH * NA + (size_t)(4 + c) * NA;
    const float* box = in + (size_t)b * NCH * NA;

    // ---- P0: zero hist (used by refine or fallback), init counters ----
    for (int i = tid; i < NBINS; i += NT) hist[i] = 0;
    if (tid == 0) { s_cnt = 0; s_cnt2 = 0; s_T1 = -1; }
    // no barrier needed before P1 (P1 doesn't touch hist; counters guarded by P1's barrier
    // only via s_cnt... s_cnt must be 0 before any atomicAdd):
    __syncthreads();

    // ---- P1: single global pass, prefilter x > 1.4 -> compact keys into cand ----
    {
        const float4* cls4 = (const float4*)cls;
        for (int q = tid; q < NA / 4; q += NT) {
            float4 v = cls4[q];
            const unsigned int i0 = (unsigned int)q * 4u;
            float xs[4] = {v.x, v.y, v.z, v.w};
#pragma unroll
            for (int t = 0; t < 4; ++t) {
                if (xs[t] > PREF_X) {
                    unsigned int p = atomicAdd(&s_cnt, 1u);
                    if (p < CAP)
                        cand[p] = ((ull)mono_key(__float_as_uint(xs[t])) << 32) |
                                  (ull)(~(i0 + t));
                }
            }
        }
    }
    __syncthreads();

    const int pcnt = (int)s_cnt;
    if (pcnt >= TARGET && pcnt <= CAP) {
        // ======== FAST PATH ========
        // ---- P2: refine histogram over the ~680 prefiltered candidates ----
        for (int e = tid; e < pcnt; e += NT) {
            unsigned int bin = (unsigned int)(cand[e] >> 52);   // key32 >> 20
            atomicAdd(&hist[bin], 1u);
        }
        __syncthreads();
        suffix_find(hist, wtot, TARGET, tid, &s_T1);
        // ---- P4: compact selected (bin >= T1) -> cand2 ----
        {
            const ull thr = (ull)(unsigned int)s_T1 << 52;
            for (int e = tid; e < pcnt; e += NT) {
                ull k = cand[e];
                if (k >= thr) {
                    unsigned int p = atomicAdd(&s_cnt2, 1u);
                    if (p < CAP) cand2[p] = k;     // hist dead; alias safe
                }
            }
        }
        __syncthreads();
    } else {
        // ======== EXACT FALLBACK (R4 algorithm) ========
        // hist is still zeroed. Full conf_pass histogram over global input.
        {
            const float4* cls4 = (const float4*)cls;
            for (int q = tid; q < NA / 4; q += NT) {
                float4 v = cls4[q];
                unsigned int kx = make_key(v.x), ky = make_key(v.y);
                unsigned int kz = make_key(v.z), kw = make_key(v.w);
                if (kx) atomicAdd(&hist[kx >> 20], 1u);
                if (ky) atomicAdd(&hist[ky >> 20], 1u);
                if (kz) atomicAdd(&hist[kz >> 20], 1u);
                if (kw) atomicAdd(&hist[kw >> 20], 1u);
            }
        }
        __syncthreads();
        suffix_find(hist, wtot, TARGET, tid, &s_T1);
        // collect bin >= T1 directly into cand2 (hist dead)
        {
            const unsigned int thrBin = (s_T1 < 0) ? 0u : (unsigned int)s_T1;
            const float4* cls4 = (const float4*)cls;
            for (int q = tid; q < NA / 4; q += NT) {
                float4 v = cls4[q];
                const unsigned int i0 = (unsigned int)q * 4u;
                unsigned int kk[4];
                kk[0] = make_key(v.x); kk[1] = make_key(v.y);
                kk[2] = make_key(v.z); kk[3] = make_key(v.w);
#pragma unroll
                for (int t = 0; t < 4; ++t) {
                    unsigned int d = kk[t];
                    if (d && (d >> 20) >= thrBin) {
                        unsigned int p = atomicAdd(&s_cnt2, 1u);
                        if (p < CAP)
                            cand2[p] = ((ull)d << 32) | (ull)(~(i0 + t));
                    }
                }
            }
        }
        __syncthreads();
    }

    const int F = min((int)s_cnt2, CAP);
    const int numSel = min(F, TOPK);

    // ---- P5a: exact sigmoid rekey (s_bits desc, idx asc) for F candidates ----
    for (int e = tid; e < F; e += NT) {
        ull k = cand2[e];
        float xv = __uint_as_float(mono_inv((unsigned int)(k >> 32)));
        float sv = sigmoidf(xv);
        cand2[e] = ((ull)__float_as_uint(sv) << 32) | (k & 0xFFFFFFFFull);
    }
    __syncthreads();

    // ---- P5b: rank-by-counting (unique keys), b128-vectorized inner loop ----
    for (int e = tid; e < F; e += NT) {
        ull k = cand2[e];
        int rank = 0;
        int o = 0;
        for (; o + 4 <= F; o += 4) {
            ulonglong2 p0 = *(const ulonglong2*)&cand2[o];
            ulonglong2 p1 = *(const ulonglong2*)&cand2[o + 2];
            rank += (p0.x > k) + (p0.y > k) + (p1.x > k) + (p1.y > k);
        }
        for (; o < F; ++o) rank += (cand2[o] > k) ? 1 : 0;
        if (rank < TOPK) skey[rank] = k;
    }
    __syncthreads();

    // ---- P6: gather boxes (cxcywh -> xyxy) as float4 + zero supmask ----
    for (int r = tid; r < numSel; r += NT) {
        ull k = skey[r];
        unsigned int i = ~(unsigned int)(k & 0xFFFFFFFFull);
        float cx = box[i];
        float cy = box[NA + i];
        float w  = box[2 * NA + i];
        float h  = box[3 * NA + i];
        float hw = w * 0.5f, hh = h * 0.5f;
        box4[r] = float4{cx - hw, cy - hh, cx + hw, cy + hh};
        bvv[r] = __uint_as_float((unsigned int)(k >> 32));
    }
    for (int t = tid; t < TOPK * 6; t += NT) sup[t] = 0ull;
    __syncthreads();

    // ---- P7: suppression masks; columns cached in registers (zero per-j LDS reads) ----
    {
        const int wave = tid >> 6;
        const int lane = tid & 63;
        float4 cb[5];
        float ca[5];
#pragma unroll
        for (int w = 0; w < 5; ++w) {
            int j = (w << 6) + lane;
            float4 v = (j < numSel) ? box4[j] : float4{0.f, 0.f, 0.f, 0.f};
            cb[w] = v;
            ca[w] = fmaxf(v.z - v.x, 0.0f) * fmaxf(v.w - v.y, 0.0f);
        }
        for (int i = wave; i < numSel; i += NW) {
            float4 bi = box4[i];   // one b128 broadcast per row
            float ai = fmaxf(bi.z - bi.x, 0.0f) * fmaxf(bi.w - bi.y, 0.0f);
            for (int w = i >> 6; w < 5; ++w) {
                const int j = (w << 6) + lane;
                bool supb = false;
                if (j < numSel && j > i) {
                    float xx1 = fmaxf(bi.x, cb[w].x);
                    float yy1 = fmaxf(bi.y, cb[w].y);
                    float xx2 = fminf(bi.z, cb[w].z);
                    float yy2 = fminf(bi.w, cb[w].w);
                    float iw = fmaxf(xx2 - xx1, 0.0f);
                    float ih = fmaxf(yy2 - yy1, 0.0f);
                    float inter = iw * ih;
                    float un = ai + ca[w] - inter;
                    float iou = inter / fmaxf(un, 1e-9f);
                    supb = iou > IOU_T;
                }
                ull bal = __ballot(supb);
                if (lane == 0) sup[i * 6 + w] = bal;
            }
        }
    }
    __syncthreads();

    // ---- P8: serial greedy scan (thread 0), next-row prefetch pipeline ----
    if (tid == 0) {
        ull rem0 = 0, rem1 = 0, rem2 = 0, rem3 = 0, rem4 = 0;
        ull n0 = sup[0], n1 = sup[1], n2 = sup[2], n3 = sup[3], n4 = sup[4];
        for (int i = 0; i < numSel; ++i) {
            ull c0 = n0, c1 = n1, c2 = n2, c3 = n3, c4 = n4;
            if (i + 1 < numSel) {
                const ull* r = &sup[(i + 1) * 6];
                n0 = r[0]; n1 = r[1]; n2 = r[2]; n3 = r[3]; n4 = r[4];
            }
            ull r_;
            switch (i >> 6) {
                case 0: r_ = rem0; break;
                case 1: r_ = rem1; break;
                case 2: r_ = rem2; break;
                case 3: r_ = rem3; break;
                default: r_ = rem4; break;
            }
            ull m = ((r_ >> (i & 63)) & 1ull) - 1ull;  // ~0 keep, 0 suppressed
            rem0 |= c0 & m; rem1 |= c1 & m; rem2 |= c2 & m;
            rem3 |= c3 & m; rem4 |= c4 & m;
        }
        keepw[0] = ~rem0; keepw[1] = ~rem1; keepw[2] = ~rem2;
        keepw[3] = ~rem3; keepw[4] = ~rem4;
    }
    __syncthreads();

    // ---- P9: write output rows ----
    float* outp = out + ((size_t)b * NC + c) * (TOPK * 6);
    for (int el = tid; el < TOPK * 6; el += NT) {
        const int r = el / 6;
        const int f = el - r * 6;
        float v = 0.0f;
        if (r < numSel && ((keepw[r >> 6] >> (r & 63)) & 1ull)) {
            float4 bb = box4[r];
            switch (f) {
                case 0: v = bb.x; break;
                case 1: v = bb.y; break;
                case 2: v = bb.z; break;
                case 3: v = bb.w; break;
                case 4: v = bvv[r]; break;
                default: v = (float)c; break;
            }
        }
        outp[el] = v;
    }
}

extern "C" void kernel_launch(void* const* d_in, const int* in_sizes, int n_in,
                              void* d_out, int out_size, void* d_ws, size_t ws_size,
                              hipStream_t stream) {
    const float* in = (const float*)d_in[0];
    float* out = (float*)d_out;
    yolo_post<<<NB * NC, NT, 0, stream>>>(in, out);
}

// Round 6
// 181.829 us; speedup vs baseline: 1.1683x; 1.1683x over previous
//
#include <hip/hip_runtime.h>
#include <cstdint>

#pragma clang fp contract(off)

#define NB      32
#define NC      18
#define NA      8400
#define NCH     (4 + NC)
#define TOPK    300
#define TARGET  316        // TOPK + margin: absorbs sigmoid-tie rank ambiguity
#define NBINS   4096
#define CAP     1024
#define CONF    0.25f
#define IOU_T   0.45f
#define NT      512
#define NW      (NT / 64)
// Prefilter: N(0,1) logits, top-316 cutoff ~1.75 +- 0.1; count(x>1.4) in [553,803] (5-sigma).
// Fast path requires TARGET <= s_cnt <= CAP, else exact fallback (R4 algorithm).
#define PREF_X  1.4f
// sigmoid(x) > 0.25  <=>  x > -ln(3). Outside [XLO,XHI] analytic compare is exact.
#define XHI     (-1.0984f)
#define XLO     (-1.0988f)

typedef unsigned long long ull;

__device__ __forceinline__ float sigmoidf(float x) {
    return 1.0f / (1.0f + expf(-x));
}
__device__ __forceinline__ unsigned int mono_key(unsigned int bits) {
    return (bits & 0x80000000u) ? ~bits : (bits | 0x80000000u);
}
__device__ __forceinline__ unsigned int mono_inv(unsigned int key) {
    return (key & 0x80000000u) ? (key ^ 0x80000000u) : ~key;
}
__device__ __forceinline__ bool conf_pass(float x) {
    if (x >= XHI) return true;
    if (x <= XLO) return false;
    return sigmoidf(x) > CONF;   // rare exact band (~1 element per task)
}
__device__ __forceinline__ unsigned int make_key(float x) {
    return conf_pass(x) ? mono_key(__float_as_uint(x)) : 0u;
}

// Suffix-find over hist: T1 s.t. count(bins > T1) < target <= count(bins >= T1).
// Requires *s_T1 == -1 on entry. Contains barriers (call from block-uniform flow).
__device__ __forceinline__ void suffix_find(unsigned int* hist, unsigned int* wtot,
                                            int target, int tid, int* s_T1) {
    const int base = tid * (NBINS / NT);   // 8 bins per thread
    unsigned int v = 0;
#pragma unroll
    for (int k = 0; k < NBINS / NT; ++k) v += hist[base + k];
    const int lane = tid & 63;
    unsigned int s = v;   // inclusive suffix sum within wave
#pragma unroll
    for (int d = 1; d < 64; d <<= 1) {
        unsigned int o = __shfl_down(s, d, 64);
        if (lane + d < 64) s += o;
    }
    if (lane == 0) wtot[tid >> 6] = s;
    __syncthreads();
    unsigned int above_waves = 0;
    for (int wv = (tid >> 6) + 1; wv < NW; ++wv) above_waves += wtot[wv];
    unsigned int acc = (s - v) + above_waves;  // strictly after this thread's chunk
    for (int bin = base + (NBINS / NT) - 1; bin >= base; --bin) {
        unsigned int cnt = hist[bin];
        if (acc < (unsigned int)target && acc + cnt >= (unsigned int)target) *s_T1 = bin;
        acc += cnt;
    }
    __syncthreads();
}

// LDS pool layout (manual phase aliasing):
//  A [0..16384):    hist (P2/fallback-hist) | cand2 @0 (8192 B) + skey @8192 (2400 B)
//  B [16384..24576): cand (ull[CAP])
//  C [24576..44976): box4 @24576 (4800) | bvv @29376 (1200) | supmask @30576 (300*48)
#define POOL_BYTES 44976
#define OFF_SKEY   8192
#define OFF_CAND   16384
#define OFF_BOX4   24576
#define OFF_BVV    29376
#define OFF_SUP    30576

__global__ __launch_bounds__(NT) void yolo_post(const float* __restrict__ in,
                                                float* __restrict__ out) {
    __shared__ __align__(16) unsigned char pool[POOL_BYTES];
    __shared__ unsigned int wtot[NW];
    __shared__ ull keepw[5];
    __shared__ unsigned int s_cnt, s_cnt2;
    __shared__ int s_T1;

    unsigned int* hist  = (unsigned int*)pool;
    ull*  cand2 = (ull*)pool;
    ull*  skey  = (ull*)(pool + OFF_SKEY);
    ull*  cand  = (ull*)(pool + OFF_CAND);
    float4* box4 = (float4*)(pool + OFF_BOX4);
    float*  bvv  = (float*)(pool + OFF_BVV);
    ull*  sup   = (ull*)(pool + OFF_SUP);   // [300][6], word 5 = pad

    const int tid = threadIdx.x;
    // XCD swizzle: image b -> XCD b%8 (blocks dispatched round-robin over 8 XCDs)
    const int x = blockIdx.x;
    const int b = (x & 7) + 8 * ((x >> 3) & 3);
    const int c = x >> 5;
    const float* cls = in + (size_t)b * NCH * NA + (size_t)(4 + c) * NA;
    const float* box = in + (size_t)b * NCH * NA;

    // ---- P0: zero hist (used by refine or fallback), init counters ----
    for (int i = tid; i < NBINS; i += NT) hist[i] = 0;
    if (tid == 0) { s_cnt = 0; s_cnt2 = 0; s_T1 = -1; }
    __syncthreads();

    // ---- P1: single global pass, prefilter x > 1.4 -> compact keys into cand ----
    {
        const float4* cls4 = (const float4*)cls;
        for (int q = tid; q < NA / 4; q += NT) {
            float4 v = cls4[q];
            const unsigned int i0 = (unsigned int)q * 4u;
            float xs[4] = {v.x, v.y, v.z, v.w};
#pragma unroll
            for (int t = 0; t < 4; ++t) {
                if (xs[t] > PREF_X) {
                    unsigned int p = atomicAdd(&s_cnt, 1u);
                    if (p < CAP)
                        cand[p] = ((ull)mono_key(__float_as_uint(xs[t])) << 32) |
                                  (ull)(~(i0 + t));
                }
            }
        }
    }
    __syncthreads();

    const int pcnt = (int)s_cnt;
    if (pcnt >= TARGET && pcnt <= CAP) {
        // ======== FAST PATH ========
        // ---- P2: refine histogram over the ~680 prefiltered candidates ----
        for (int e = tid; e < pcnt; e += NT) {
            unsigned int bin = (unsigned int)(cand[e] >> 52);   // key32 >> 20
            atomicAdd(&hist[bin], 1u);
        }
        __syncthreads();
        suffix_find(hist, wtot, TARGET, tid, &s_T1);
        // ---- P4: compact selected (bin >= T1) -> cand2 ----
        {
            const ull thr = (ull)(unsigned int)s_T1 << 52;
            for (int e = tid; e < pcnt; e += NT) {
                ull k = cand[e];
                if (k >= thr) {
                    unsigned int p = atomicAdd(&s_cnt2, 1u);
                    if (p < CAP) cand2[p] = k;     // hist dead; alias safe
                }
            }
        }
        __syncthreads();
    } else {
        // ======== EXACT FALLBACK (R4 algorithm) ========
        // hist is still zeroed. Full conf_pass histogram over global input.
        {
            const float4* cls4 = (const float4*)cls;
            for (int q = tid; q < NA / 4; q += NT) {
                float4 v = cls4[q];
                unsigned int kx = make_key(v.x), ky = make_key(v.y);
                unsigned int kz = make_key(v.z), kw = make_key(v.w);
                if (kx) atomicAdd(&hist[kx >> 20], 1u);
                if (ky) atomicAdd(&hist[ky >> 20], 1u);
                if (kz) atomicAdd(&hist[kz >> 20], 1u);
                if (kw) atomicAdd(&hist[kw >> 20], 1u);
            }
        }
        __syncthreads();
        suffix_find(hist, wtot, TARGET, tid, &s_T1);
        // collect bin >= T1 directly into cand2 (hist dead)
        {
            const unsigned int thrBin = (s_T1 < 0) ? 0u : (unsigned int)s_T1;
            const float4* cls4 = (const float4*)cls;
            for (int q = tid; q < NA / 4; q += NT) {
                float4 v = cls4[q];
                const unsigned int i0 = (unsigned int)q * 4u;
                unsigned int kk[4];
                kk[0] = make_key(v.x); kk[1] = make_key(v.y);
                kk[2] = make_key(v.z); kk[3] = make_key(v.w);
#pragma unroll
                for (int t = 0; t < 4; ++t) {
                    unsigned int d = kk[t];
                    if (d && (d >> 20) >= thrBin) {
                        unsigned int p = atomicAdd(&s_cnt2, 1u);
                        if (p < CAP)
                            cand2[p] = ((ull)d << 32) | (ull)(~(i0 + t));
                    }
                }
            }
        }
        __syncthreads();
    }

    const int F = min((int)s_cnt2, CAP);
    const int numSel = min(F, TOPK);

    // ---- P5a: exact sigmoid rekey (s_bits desc, idx asc) for F candidates ----
    for (int e = tid; e < F; e += NT) {
        ull k = cand2[e];
        float xv = __uint_as_float(mono_inv((unsigned int)(k >> 32)));
        float sv = sigmoidf(xv);
        cand2[e] = ((ull)__float_as_uint(sv) << 32) | (k & 0xFFFFFFFFull);
    }
    __syncthreads();

    // ---- P5b: rank-by-counting (unique keys), b128-vectorized inner loop ----
    for (int e = tid; e < F; e += NT) {
        ull k = cand2[e];
        int rank = 0;
        int o = 0;
        for (; o + 4 <= F; o += 4) {
            ulonglong2 p0 = *(const ulonglong2*)&cand2[o];
            ulonglong2 p1 = *(const ulonglong2*)&cand2[o + 2];
            rank += (p0.x > k) + (p0.y > k) + (p1.x > k) + (p1.y > k);
        }
        for (; o < F; ++o) rank += (cand2[o] > k) ? 1 : 0;
        if (rank < TOPK) skey[rank] = k;
    }
    __syncthreads();

    // ---- P6: gather boxes (cxcywh -> xyxy) as float4 + zero supmask ----
    for (int r = tid; r < numSel; r += NT) {
        ull k = skey[r];
        unsigned int i = ~(unsigned int)(k & 0xFFFFFFFFull);
        float cx = box[i];
        float cy = box[NA + i];
        float w  = box[2 * NA + i];
        float h  = box[3 * NA + i];
        float hw = w * 0.5f, hh = h * 0.5f;
        box4[r] = float4{cx - hw, cy - hh, cx + hw, cy + hh};
        bvv[r] = __uint_as_float((unsigned int)(k >> 32));
    }
    for (int t = tid; t < TOPK * 6; t += NT) sup[t] = 0ull;
    __syncthreads();

    // ---- P7: suppression masks; columns cached in registers.
    //      w-loop is CONSTANT-TRIP + fully unrolled with a wave-uniform skip so
    //      cb[]/ca[] stay constant-indexed -> VGPRs (dynamic start caused scratch
    //      spill in R5: WRITE_SIZE 4->27 MB). ----
    {
        const int wave = tid >> 6;
        const int lane = tid & 63;
        float4 cb[5];
        float ca[5];
#pragma unroll
        for (int w = 0; w < 5; ++w) {
            int j = (w << 6) + lane;
            float4 v = (j < numSel) ? box4[j] : float4{0.f, 0.f, 0.f, 0.f};
            cb[w] = v;
            ca[w] = fmaxf(v.z - v.x, 0.0f) * fmaxf(v.w - v.y, 0.0f);
        }
        for (int i = wave; i < numSel; i += NW) {
            float4 bi = box4[i];   // one b128 broadcast per row
            float ai = fmaxf(bi.z - bi.x, 0.0f) * fmaxf(bi.w - bi.y, 0.0f);
            const int w0 = i >> 6;   // wave-uniform
#pragma unroll
            for (int w = 0; w < 5; ++w) {
                if (w < w0) continue;   // uniform branch, cb[w] stays register-resident
                const int j = (w << 6) + lane;
                bool supb = false;
                if (j < numSel && j > i) {
                    float xx1 = fmaxf(bi.x, cb[w].x);
                    float yy1 = fmaxf(bi.y, cb[w].y);
                    float xx2 = fminf(bi.z, cb[w].z);
                    float yy2 = fminf(bi.w, cb[w].w);
                    float iw = fmaxf(xx2 - xx1, 0.0f);
                    float ih = fmaxf(yy2 - yy1, 0.0f);
                    float inter = iw * ih;
                    float un = ai + ca[w] - inter;
                    float iou = inter / fmaxf(un, 1e-9f);
                    supb = iou > IOU_T;
                }
                ull bal = __ballot(supb);
                if (lane == 0) sup[i * 6 + w] = bal;
            }
        }
    }
    __syncthreads();

    // ---- P8: serial greedy scan (thread 0), next-row prefetch pipeline ----
    if (tid == 0) {
        ull rem0 = 0, rem1 = 0, rem2 = 0, rem3 = 0, rem4 = 0;
        ull n0 = sup[0], n1 = sup[1], n2 = sup[2], n3 = sup[3], n4 = sup[4];
        for (int i = 0; i < numSel; ++i) {
            ull c0 = n0, c1 = n1, c2 = n2, c3 = n3, c4 = n4;
            if (i + 1 < numSel) {
                const ull* r = &sup[(i + 1) * 6];
                n0 = r[0]; n1 = r[1]; n2 = r[2]; n3 = r[3]; n4 = r[4];
            }
            ull r_;
            switch (i >> 6) {
                case 0: r_ = rem0; break;
                case 1: r_ = rem1; break;
                case 2: r_ = rem2; break;
                case 3: r_ = rem3; break;
                default: r_ = rem4; break;
            }
            ull m = ((r_ >> (i & 63)) & 1ull) - 1ull;  // ~0 keep, 0 suppressed
            rem0 |= c0 & m; rem1 |= c1 & m; rem2 |= c2 & m;
            rem3 |= c3 & m; rem4 |= c4 & m;
        }
        keepw[0] = ~rem0; keepw[1] = ~rem1; keepw[2] = ~rem2;
        keepw[3] = ~rem3; keepw[4] = ~rem4;
    }
    __syncthreads();

    // ---- P9: write output rows ----
    float* outp = out + ((size_t)b * NC + c) * (TOPK * 6);
    for (int el = tid; el < TOPK * 6; el += NT) {
        const int r = el / 6;
        const int f = el - r * 6;
        float v = 0.0f;
        if (r < numSel && ((keepw[r >> 6] >> (r & 63)) & 1ull)) {
            float4 bb = box4[r];
            switch (f) {
                case 0: v = bb.x; break;
                case 1: v = bb.y; break;
                case 2: v = bb.z; break;
                case 3: v = bb.w; break;
                case 4: v = bvv[r]; break;
                default: v = (float)c; break;
            }
        }
        outp[el] = v;
    }
}

extern "C" void kernel_launch(void* const* d_in, const int* in_sizes, int n_in,
                              void* d_out, int out_size, void* d_ws, size_t ws_size,
                              hipStream_t stream) {
    const float* in = (const float*)d_in[0];
    float* out = (float*)d_out;
    yolo_post<<<NB * NC, NT, 0, stream>>>(in, out);
}

// Round 7
// 178.709 us; speedup vs baseline: 1.1887x; 1.0175x over previous
//
#include <hip/hip_runtime.h>
#include <cstdint>

#pragma clang fp contract(off)

#define NB      32
#define NC      18
#define NA      8400
#define NCH     (4 + NC)
#define TOPK    300
#define TARGET  316        // TOPK + margin: absorbs sigmoid-tie rank ambiguity
#define NBINS   2048
#define CAP     1024
#define CONF    0.25f
#define IOU_T   0.45f
#define NT      512
#define NW      (NT / 64)
// Prefilter: N(0,1) logits, top-316 cutoff ~1.75 +- 0.1; count(x>1.4) in [553,803] (5-sigma).
// Fast path requires TARGET <= s_cnt <= CAP, else exact fallback.
#define PREF_X  1.4f
// sigmoid(x) > 0.25  <=>  x > -ln(3). Outside [XLO,XHI] analytic compare is exact.
#define XHI     (-1.0984f)
#define XLO     (-1.0988f)

// Fast-path binning: keys (mono_key of x>1.4) start at 0xBFB33333.
// bin width 2^14 key-ULPs ~ 0.002 in x near cutoff -> ~1.4 cands/bin.
#define FAST_KBASE 0xBFB00000u
#define FAST_SHIFT 14
// Fallback binning: conf_pass keys start ~0x40735C26.
#define FB_KBASE   0x40000000u
#define FB_SHIFT   21

typedef unsigned long long ull;

__device__ __forceinline__ float sigmoidf(float x) {
    return 1.0f / (1.0f + expf(-x));
}
__device__ __forceinline__ unsigned int mono_key(unsigned int bits) {
    return (bits & 0x80000000u) ? ~bits : (bits | 0x80000000u);
}
__device__ __forceinline__ unsigned int mono_inv(unsigned int key) {
    return (key & 0x80000000u) ? (key ^ 0x80000000u) : ~key;
}
__device__ __forceinline__ bool conf_pass(float x) {
    if (x >= XHI) return true;
    if (x <= XLO) return false;
    return sigmoidf(x) > CONF;   // rare exact band (~1 element per task)
}
__device__ __forceinline__ unsigned int make_key(float x) {
    return conf_pass(x) ? mono_key(__float_as_uint(x)) : 0u;
}
__device__ __forceinline__ unsigned int bin_fast(unsigned int k) {
    return min((k - FAST_KBASE) >> FAST_SHIFT, (unsigned)(NBINS - 1));
}
__device__ __forceinline__ unsigned int bin_fb(unsigned int k) {
    return min((k - FB_KBASE) >> FB_SHIFT, (unsigned)(NBINS - 1));
}

// Suffix-find over hist: T1 s.t. count(bins > T1) < target <= count(bins >= T1).
// Requires *s_T1 == -1 on entry. Contains barriers (block-uniform flow only).
__device__ __forceinline__ void suffix_find(unsigned int* hist, unsigned int* wtot,
                                            int target, int tid, int* s_T1) {
    const int base = tid * (NBINS / NT);   // 4 bins per thread
    unsigned int v = 0;
#pragma unroll
    for (int k = 0; k < NBINS / NT; ++k) v += hist[base + k];
    const int lane = tid & 63;
    unsigned int s = v;   // inclusive suffix sum within wave
#pragma unroll
    for (int d = 1; d < 64; d <<= 1) {
        unsigned int o = __shfl_down(s, d, 64);
        if (lane + d < 64) s += o;
    }
    if (lane == 0) wtot[tid >> 6] = s;
    __syncthreads();
    unsigned int above_waves = 0;
    for (int wv = (tid >> 6) + 1; wv < NW; ++wv) above_waves += wtot[wv];
    unsigned int acc = (s - v) + above_waves;  // strictly after this thread's chunk
    for (int bin = base + (NBINS / NT) - 1; bin >= base; --bin) {
        unsigned int cnt = hist[bin];
        if (acc < (unsigned int)target && acc + cnt >= (unsigned int)target) *s_T1 = bin;
        acc += cnt;
    }
    __syncthreads();
}

// LDS pool phase-aliasing map (17.6 KB total):
//  [0,8192):      hist (P0..suffix) -> cand2 (P4..P5b) -> sup[0:8192) (P6b..P8)
//  [8192,16384):  cand (P1..P4) -> skey@8192 (P5b..P6a) -> sup[8192:12000) (P6b..P8)
//  [12000,16800): box4 (P6a..P9)
//  [16800,18000): bvv  (P6a..P9)
#define OFF_CAND   8192
#define OFF_SKEY   8192
#define OFF_SUP    0
#define OFF_BOX4   12000
#define OFF_BVV    16800
#define POOL_BYTES 18000

__global__ __launch_bounds__(NT) void yolo_post(const float* __restrict__ in,
                                                float* __restrict__ out) {
    __shared__ __align__(16) unsigned char pool[POOL_BYTES];
    __shared__ unsigned int wtot[NW];
    __shared__ ull keepw[5];
    __shared__ unsigned int s_cnt, s_cnt2;
    __shared__ int s_T1;

    unsigned int* hist = (unsigned int*)pool;
    ull*  cand2 = (ull*)pool;
    ull*  cand  = (ull*)(pool + OFF_CAND);
    ull*  skey  = (ull*)(pool + OFF_SKEY);
    ull*  sup   = (ull*)(pool + OFF_SUP);    // [300][5]
    float4* box4 = (float4*)(pool + OFF_BOX4);
    float*  bvv  = (float*)(pool + OFF_BVV);

    const int tid = threadIdx.x;
    const int lane = tid & 63;
    // XCD swizzle: image b -> XCD b%8 (round-robin dispatch over 8 XCDs)
    const int x = blockIdx.x;
    const int b = (x & 7) + 8 * ((x >> 3) & 3);
    const int c = x >> 5;
    const float* cls = in + (size_t)b * NCH * NA + (size_t)(4 + c) * NA;
    const float* box = in + (size_t)b * NCH * NA;

    // ---- P0: zero hist, init counters ----
    for (int i = tid; i < NBINS; i += NT) hist[i] = 0;
    if (tid == 0) { s_cnt = 0; s_cnt2 = 0; s_T1 = -1; }
    __syncthreads();

    // ---- P1: global pass, prefilter x>1.4, wave-aggregated compaction into cand ----
    {
        const float4* cls4 = (const float4*)cls;
        const ull ltm = (1ull << lane) - 1ull;   // lanes below me
        for (int q = tid; q < NA / 4; q += NT) {
            float4 v = cls4[q];
            const unsigned int i0 = (unsigned int)q * 4u;
            float xs[4] = {v.x, v.y, v.z, v.w};
            ull m[4];
            unsigned int cnt = 0;
#pragma unroll
            for (int t = 0; t < 4; ++t) {
                m[t] = __ballot(xs[t] > PREF_X);
                cnt += (unsigned int)__popcll(m[t]);
            }
            if (cnt) {
                unsigned int base = 0;
                if (lane == 0) base = atomicAdd(&s_cnt, cnt);
                base = (unsigned int)__builtin_amdgcn_readfirstlane((int)base);
                unsigned int pre = 0;
#pragma unroll
                for (int t = 0; t < 4; ++t) {
                    if (xs[t] > PREF_X) {
                        unsigned int p = base + pre + (unsigned int)__popcll(m[t] & ltm);
                        if (p < CAP)
                            cand[p] = ((ull)mono_key(__float_as_uint(xs[t])) << 32) |
                                      (ull)(~(i0 + t));
                    }
                    pre += (unsigned int)__popcll(m[t]);
                }
            }
        }
    }
    __syncthreads();

    const int pcnt = (int)s_cnt;
    if (pcnt >= TARGET && pcnt <= CAP) {
        // ======== FAST PATH ========
        // ---- P2: refine histogram over prefiltered candidates (range binning) ----
        for (int e = tid; e < pcnt; e += NT) {
            unsigned int k32 = (unsigned int)(cand[e] >> 32);
            atomicAdd(&hist[bin_fast(k32)], 1u);
        }
        __syncthreads();
        suffix_find(hist, wtot, TARGET, tid, &s_T1);
        // ---- P4: compact selected (key >= threshold of bin T1) -> cand2 ----
        {
            const ull thr = ((ull)FAST_KBASE + ((ull)(unsigned int)s_T1 << FAST_SHIFT)) << 32;
            for (int e = tid; e < pcnt; e += NT) {
                ull k = cand[e];
                if (k >= thr) {
                    unsigned int p = atomicAdd(&s_cnt2, 1u);
                    if (p < CAP) cand2[p] = k;     // hist dead; alias safe
                }
            }
        }
        __syncthreads();
    } else {
        // ======== EXACT FALLBACK ========
        {
            const float4* cls4 = (const float4*)cls;
            for (int q = tid; q < NA / 4; q += NT) {
                float4 v = cls4[q];
                unsigned int kx = make_key(v.x), ky = make_key(v.y);
                unsigned int kz = make_key(v.z), kw = make_key(v.w);
                if (kx) atomicAdd(&hist[bin_fb(kx)], 1u);
                if (ky) atomicAdd(&hist[bin_fb(ky)], 1u);
                if (kz) atomicAdd(&hist[bin_fb(kz)], 1u);
                if (kw) atomicAdd(&hist[bin_fb(kw)], 1u);
            }
        }
        __syncthreads();
        suffix_find(hist, wtot, TARGET, tid, &s_T1);
        // collect key >= threshold into cand2 (hist dead after suffix_find barrier)
        {
            const ull thr = (s_T1 < 0) ? 0ull
                : ((ull)FB_KBASE + ((ull)(unsigned int)s_T1 << FB_SHIFT));
            const float4* cls4 = (const float4*)cls;
            for (int q = tid; q < NA / 4; q += NT) {
                float4 v = cls4[q];
                const unsigned int i0 = (unsigned int)q * 4u;
                unsigned int kk[4];
                kk[0] = make_key(v.x); kk[1] = make_key(v.y);
                kk[2] = make_key(v.z); kk[3] = make_key(v.w);
#pragma unroll
                for (int t = 0; t < 4; ++t) {
                    unsigned int d = kk[t];
                    if (d && (ull)d >= thr) {
                        unsigned int p = atomicAdd(&s_cnt2, 1u);
                        if (p < CAP)
                            cand2[p] = ((ull)d << 32) | (ull)(~(i0 + t));
                    }
                }
            }
        }
        __syncthreads();
    }

    const int F = min((int)s_cnt2, CAP);
    const int numSel = min(F, TOPK);

    // ---- P5a: exact sigmoid rekey (s_bits desc, idx asc) for F candidates ----
    for (int e = tid; e < F; e += NT) {
        ull k = cand2[e];
        float xv = __uint_as_float(mono_inv((unsigned int)(k >> 32)));
        float sv = sigmoidf(xv);
        cand2[e] = ((ull)__float_as_uint(sv) << 32) | (k & 0xFFFFFFFFull);
    }
    __syncthreads();

    // ---- P5b: rank-by-counting (unique keys), b128-vectorized inner loop ----
    for (int e = tid; e < F; e += NT) {
        ull k = cand2[e];
        int rank = 0;
        int o = 0;
        for (; o + 4 <= F; o += 4) {
            ulonglong2 p0 = *(const ulonglong2*)&cand2[o];
            ulonglong2 p1 = *(const ulonglong2*)&cand2[o + 2];
            rank += (p0.x > k) + (p0.y > k) + (p1.x > k) + (p1.y > k);
        }
        for (; o < F; ++o) rank += (cand2[o] > k) ? 1 : 0;
        if (rank < TOPK) skey[rank] = k;   // cand region dead after P4
    }
    __syncthreads();

    // ---- P6a: gather boxes (cxcywh -> xyxy) as float4 ----
    for (int r = tid; r < numSel; r += NT) {
        ull k = skey[r];
        unsigned int i = ~(unsigned int)(k & 0xFFFFFFFFull);
        float cx = box[i];
        float cy = box[NA + i];
        float w  = box[2 * NA + i];
        float h  = box[3 * NA + i];
        float hw = w * 0.5f, hh = h * 0.5f;
        box4[r] = float4{cx - hw, cy - hh, cx + hw, cy + hh};
        bvv[r] = __uint_as_float((unsigned int)(k >> 32));
    }
    __syncthreads();   // skey consumed; sup region (aliases skey) may now be zeroed

    // ---- P6b: zero supmask ----
    for (int t = tid; t < TOPK * 5; t += NT) sup[t] = 0ull;
    __syncthreads();

    // ---- P7: suppression masks; columns cached in registers (const-indexed,
    //      wave-uniform skip keeps them in VGPRs — dynamic indexing spills) ----
    {
        const int wave = tid >> 6;
        float4 cb[5];
        float ca[5];
#pragma unroll
        for (int w = 0; w < 5; ++w) {
            int j = (w << 6) + lane;
            float4 v = (j < numSel) ? box4[j] : float4{0.f, 0.f, 0.f, 0.f};
            cb[w] = v;
            ca[w] = fmaxf(v.z - v.x, 0.0f) * fmaxf(v.w - v.y, 0.0f);
        }
        for (int i = wave; i < numSel; i += NW) {
            float4 bi = box4[i];   // one b128 broadcast per row
            float ai = fmaxf(bi.z - bi.x, 0.0f) * fmaxf(bi.w - bi.y, 0.0f);
            const int w0 = i >> 6;   // wave-uniform
#pragma unroll
            for (int w = 0; w < 5; ++w) {
                if (w < w0) continue;   // uniform branch
                const int j = (w << 6) + lane;
                bool supb = false;
                if (j < numSel && j > i) {
                    float xx1 = fmaxf(bi.x, cb[w].x);
                    float yy1 = fmaxf(bi.y, cb[w].y);
                    float xx2 = fminf(bi.z, cb[w].z);
                    float yy2 = fminf(bi.w, cb[w].w);
                    float iw = fmaxf(xx2 - xx1, 0.0f);
                    float ih = fmaxf(yy2 - yy1, 0.0f);
                    float inter = iw * ih;
                    float un = ai + ca[w] - inter;
                    float iou = inter / fmaxf(un, 1e-9f);
                    supb = iou > IOU_T;
                }
                ull bal = __ballot(supb);
                if (lane == 0) sup[i * 5 + w] = bal;
            }
        }
    }
    __syncthreads();

    // ---- P8: serial greedy scan (thread 0), next-row prefetch ----
    if (tid == 0) {
        ull rem0 = 0, rem1 = 0, rem2 = 0, rem3 = 0, rem4 = 0;
        ull n0 = sup[0], n1 = sup[1], n2 = sup[2], n3 = sup[3], n4 = sup[4];
        for (int i = 0; i < numSel; ++i) {
            ull c0 = n0, c1 = n1, c2 = n2, c3 = n3, c4 = n4;
            if (i + 1 < numSel) {
                const ull* r = &sup[(i + 1) * 5];
                n0 = r[0]; n1 = r[1]; n2 = r[2]; n3 = r[3]; n4 = r[4];
            }
            ull r_;
            switch (i >> 6) {
                case 0: r_ = rem0; break;
                case 1: r_ = rem1; break;
                case 2: r_ = rem2; break;
                case 3: r_ = rem3; break;
                default: r_ = rem4; break;
            }
            ull m = ((r_ >> (i & 63)) & 1ull) - 1ull;  // ~0 keep, 0 suppressed
            rem0 |= c0 & m; rem1 |= c1 & m; rem2 |= c2 & m;
            rem3 |= c3 & m; rem4 |= c4 & m;
        }
        keepw[0] = ~rem0; keepw[1] = ~rem1; keepw[2] = ~rem2;
        keepw[3] = ~rem3; keepw[4] = ~rem4;
    }
    __syncthreads();

    // ---- P9: write output rows ----
    float* outp = out + ((size_t)b * NC + c) * (TOPK * 6);
    for (int el = tid; el < TOPK * 6; el += NT) {
        const int r = el / 6;
        const int f = el - r * 6;
        float v = 0.0f;
        if (r < numSel && ((keepw[r >> 6] >> (r & 63)) & 1ull)) {
            float4 bb = box4[r];
            switch (f) {
                case 0: v = bb.x; break;
                case 1: v = bb.y; break;
                case 2: v = bb.z; break;
                case 3: v = bb.w; break;
                case 4: v = bvv[r]; break;
                default: v = (float)c; break;
            }
        }
        outp[el] = v;
    }
}

extern "C" void kernel_launch(void* const* d_in, const int* in_sizes, int n_in,
                              void* d_out, int out_size, void* d_ws, size_t ws_size,
                              hipStream_t stream) {
    const float* in = (const float*)d_in[0];
    float* out = (float*)d_out;
    yolo_post<<<NB * NC, NT, 0, stream>>>(in, out);
}